// Round 1
// baseline (1088.516 us; speedup 1.0000x reference)
//
#include <hip/hip_runtime.h>
#include <stdint.h>

// CCLayer: ZPi (288 x 262144) f32, U (256 x 32) f32, alpha (32) f32.
// Z = ZPi[:256], Pi = ZPi[256:].
// out[:256] = Z * sum_pi + U @ ((alpha - U^T Z) * Pi);  out[256:] = Pi.
//
// v2 strategy: Z tile lives in LDS, not VGPRs.
//  - Stage Z (256 rows x 64 cols, 64 KB) via global_load_lds width=16:
//    one HBM read of Z total; both FMA passes stream z from LDS.
//  - Cross-wave utz reduction via ds_add_f32 atomics into an 8 KB buffer
//    (replaces the previous 64 KB utz_part staging array).
//  - Per-thread live set is only utz[32] (pass 1) / w[32] (pass 2), so the
//    allocator keeps everything in VGPRs (v1's z[32] forced rematerialization:
//    VGPR_Count=52 proved Z was silently re-read from global in the epilogue).
// LDS total 74 KB -> 2 blocks/CU (16 waves/CU).

#define NCOLS 262144
#define DROWS 256
#define PROWS 32

__device__ __forceinline__ void gload_lds16(const float* g, float* l) {
    __builtin_amdgcn_global_load_lds(
        (const __attribute__((address_space(1))) void*)g,
        (__attribute__((address_space(3))) void*)l,
        16, 0, 0);
}

__global__ __launch_bounds__(512, 4) void CCLayer_kernel(
    const float* __restrict__ ZPi,
    const float* __restrict__ U,
    const float* __restrict__ alpha,
    float* __restrict__ out)
{
    __shared__ __align__(16) float zl[DROWS][64];    // 64 KB  Z tile
    __shared__ __align__(16) float wbuf[PROWS][64];  //  8 KB  utz sum -> w
    __shared__ float sp[8][64];                      //  2 KB  per-wave pi sums

    const int lane = threadIdx.x & 63;
    const int q = __builtin_amdgcn_readfirstlane((int)(threadIdx.x >> 6)); // wave id
    const int n0 = blockIdx.x * 64;
    const int n  = n0 + lane;

    // ---- stage Z tile into LDS: wave q stages rows q*32..q*32+31, 4 rows/instr ----
    {
        const int sub = lane >> 4;          // 0..3   row within quad
        const int c4  = (lane & 15) << 2;   // col group (4 floats = 16 B)
        #pragma unroll
        for (int i = 0; i < 8; ++i) {
            const int r0 = (q << 5) + (i << 2);
            const float* src = ZPi + (size_t)(r0 + sub) * NCOLS + (n0 + c4);
            gload_lds16(src, &zl[r0][0]);   // LDS dst wave-uniform, lane*16B linear
        }
    }

    // ---- zero wbuf for the ds_add reduction (512 threads x float4 = 2048 f) ----
    ((float4*)wbuf)[threadIdx.x] = make_float4(0.f, 0.f, 0.f, 0.f);

    // ---- Pi: each thread owns rows p = q*4+j at its column; passthrough + psum ----
    float pi[4];
    float psum = 0.f;
    #pragma unroll
    for (int j = 0; j < 4; ++j) {
        const int p = (q << 2) + j;
        const size_t idx = (size_t)(DROWS + p) * NCOLS + n;
        const float v = ZPi[idx];
        pi[j] = v;
        out[idx] = v;
        psum += v;
    }
    sp[q][lane] = psum;

    __syncthreads();   // drains vmcnt (staging) + lgkm; zl/wbuf/sp ready

    // ---- pass 1: utz[p] partials over this wave's 32 rows, z streamed from LDS ----
    float utz[PROWS];
    #pragma unroll
    for (int p = 0; p < PROWS; ++p) utz[p] = 0.f;

    #pragma unroll
    for (int d = 0; d < 32; ++d) {
        const float zd = zl[(q << 5) + d][lane];                  // ds_read, 2-way = free
        const float* urow = U + (size_t)((q << 5) + d) * PROWS;   // uniform -> s_load
        #pragma unroll
        for (int p = 0; p < PROWS; ++p)
            utz[p] = __builtin_fmaf(urow[p], zd, utz[p]);
    }
    #pragma unroll
    for (int p = 0; p < PROWS; ++p)
        atomicAdd(&wbuf[p][lane], utz[p]);   // ds_add_f32, no return

    __syncthreads();

    // ---- finalize w for this thread's 4 p rows: w = (alpha - utz_total) * pi ----
    #pragma unroll
    for (int j = 0; j < 4; ++j) {
        const int p = (q << 2) + j;
        wbuf[p][lane] = (alpha[p] - wbuf[p][lane]) * pi[j];
    }
    __syncthreads();

    // ---- s (column pi-sum) and w into registers ----
    float s = 0.f;
    #pragma unroll
    for (int qq = 0; qq < 8; ++qq) s += sp[qq][lane];

    float w[PROWS];
    #pragma unroll
    for (int p = 0; p < PROWS; ++p) w[p] = wbuf[p][lane];

    // ---- pass 2: out[d] = s*z[d] + sum_p U[d][p]*w[p], z streamed from LDS ----
    float* obase = out + (size_t)(q << 5) * NCOLS + n;
    #pragma unroll
    for (int d = 0; d < 32; ++d) {
        const float zd = zl[(q << 5) + d][lane];
        const float* urow = U + (size_t)((q << 5) + d) * PROWS;   // uniform -> s_load
        float acc = s * zd;
        #pragma unroll
        for (int p = 0; p < PROWS; ++p)
            acc = __builtin_fmaf(urow[p], w[p], acc);
        obase[(size_t)d * NCOLS] = acc;
    }
}

extern "C" void kernel_launch(void* const* d_in, const int* in_sizes, int n_in,
                              void* d_out, int out_size, void* d_ws, size_t ws_size,
                              hipStream_t stream) {
    const float* ZPi   = (const float*)d_in[0];
    const float* U     = (const float*)d_in[1];
    const float* alpha = (const float*)d_in[2];
    float* out = (float*)d_out;

    dim3 grid(NCOLS / 64);   // 4096 blocks
    dim3 block(512);         // 8 waves
    CCLayer_kernel<<<grid, block, 0, stream>>>(ZPi, U, alpha, out);
}

// Round 2
// 665.305 us; speedup vs baseline: 1.6361x; 1.6361x over previous
//
#include <hip/hip_runtime.h>
#include <stdint.h>

// CCLayer: ZPi (288 x 262144) f32, U (256 x 32) f32, alpha (32) f32.
// Z = ZPi[:256], Pi = ZPi[256:].
// out[:256] = Z * sum_pi + U @ ((alpha - U^T Z) * Pi);  out[256:] = Pi.
//
// v3: latency-bound fix. No Z staging (L3 absorbs the second read -- proven
// by round-0 counters: FETCH 240 MB < 302 MB input). float2 per lane doubles
// bytes-in-flight and amortizes each scalar U operand over 2 columns. LDS cut
// from 74 KB to 18 KB -> 4 blocks/CU (vs 2), waves progress independently
// (no staging barrier). Nontemporal output stores keep L2/L3 clean for the
// pass-2 Z re-read (WRITE_SIZE was 486 MB vs 302 MB ideal = write-allocate
// pollution).
//
// Mapping: block = 256 thr = 4 waves, tile = 128 cols. All waves cover the
// same 128 cols (lane owns cols 2*lane, 2*lane+1); wave q owns d-rows
// q*64..q*64+63. Cross-wave utz reduction via ds_add_f32 into wbuf.

#define NCOLS 262144
#define DROWS 256
#define PROWS 32
#define TILE  128
#define NWAVE 4
#define RPW   64   // d-rows per wave

typedef float v2f __attribute__((ext_vector_type(2)));

__global__ __launch_bounds__(256, 4) void CCLayer_kernel(
    const float* __restrict__ ZPi,
    const float* __restrict__ U,
    const float* __restrict__ alpha,
    float* __restrict__ out)
{
    __shared__ float wbuf[PROWS][TILE];  // 16 KB: utz partial sums -> w
    __shared__ float sp[NWAVE][TILE];    //  2 KB: per-wave pi column sums

    const int lane = threadIdx.x & 63;
    const int q    = __builtin_amdgcn_readfirstlane((int)(threadIdx.x >> 6));
    const int n0   = blockIdx.x * TILE;
    const int c0   = lane * 2;               // column pair within tile
    const size_t gc = (size_t)n0 + c0;       // global column

    // ---- zero wbuf (4096 floats, 256 threads x 4 float4, coalesced) ----
    {
        float4* wb4 = (float4*)&wbuf[0][0];
        #pragma unroll
        for (int i = 0; i < 4; ++i)
            wb4[threadIdx.x + 256 * i] = make_float4(0.f, 0.f, 0.f, 0.f);
    }

    // ---- Pi: wave q owns rows q*8..q*8+7; passthrough + column partial sum ----
    v2f pi[8];
    v2f ps = {0.f, 0.f};
    #pragma unroll
    for (int j = 0; j < 8; ++j) {
        const int p = q * 8 + j;
        const size_t off = (size_t)(DROWS + p) * NCOLS + gc;
        const v2f v = *(const v2f*)(ZPi + off);
        pi[j] = v;
        __builtin_nontemporal_store(v, (v2f*)(out + off));
        ps += v;
    }
    sp[q][c0]     = ps.x;
    sp[q][c0 + 1] = ps.y;

    __syncthreads();   // wbuf zeroed + sp visible

    // ---- pass 1: utz[p] partials over this wave's 64 d-rows ----
    v2f utz[PROWS];
    #pragma unroll
    for (int p = 0; p < PROWS; ++p) utz[p] = (v2f){0.f, 0.f};

    const float* zbase = ZPi + (size_t)(q * RPW) * NCOLS + gc;
    const float* ubase = U + q * RPW * PROWS;

    #pragma unroll 8
    for (int d = 0; d < RPW; ++d) {
        const v2f z2 = *(const v2f*)(zbase + (size_t)d * NCOLS);
        const float* urow = ubase + d * PROWS;   // uniform -> s_load
        #pragma unroll
        for (int p = 0; p < PROWS; ++p) {
            utz[p].x = __builtin_fmaf(urow[p], z2.x, utz[p].x);
            utz[p].y = __builtin_fmaf(urow[p], z2.y, utz[p].y);
        }
    }
    #pragma unroll
    for (int p = 0; p < PROWS; ++p) {
        atomicAdd(&wbuf[p][c0],     utz[p].x);   // ds_add_f32
        atomicAdd(&wbuf[p][c0 + 1], utz[p].y);
    }

    __syncthreads();

    // ---- finalize w rows q*8..q*8+7: w = (alpha - utz_total) * pi ----
    #pragma unroll
    for (int j = 0; j < 8; ++j) {
        const int p = q * 8 + j;
        const float a = alpha[p];                // uniform -> s_load
        wbuf[p][c0]     = (a - wbuf[p][c0])     * pi[j].x;
        wbuf[p][c0 + 1] = (a - wbuf[p][c0 + 1]) * pi[j].y;
    }

    __syncthreads();

    // ---- s (column pi-sum) and w into registers ----
    v2f s2 = {0.f, 0.f};
    #pragma unroll
    for (int qq = 0; qq < NWAVE; ++qq) {
        s2.x += sp[qq][c0];
        s2.y += sp[qq][c0 + 1];
    }
    v2f w[PROWS];
    #pragma unroll
    for (int p = 0; p < PROWS; ++p)
        w[p] = *(const v2f*)&wbuf[p][c0];

    // ---- pass 2: out[d] = s*z[d] + sum_p U[d][p]*w[p] (Z re-read rides L3) ----
    float* obase = out + (size_t)(q * RPW) * NCOLS + gc;
    #pragma unroll 8
    for (int d = 0; d < RPW; ++d) {
        const v2f z2 = *(const v2f*)(zbase + (size_t)d * NCOLS);
        const float* urow = ubase + d * PROWS;   // uniform -> s_load
        v2f acc = {s2.x * z2.x, s2.y * z2.y};
        #pragma unroll
        for (int p = 0; p < PROWS; ++p) {
            acc.x = __builtin_fmaf(urow[p], w[p].x, acc.x);
            acc.y = __builtin_fmaf(urow[p], w[p].y, acc.y);
        }
        __builtin_nontemporal_store(acc, (v2f*)(obase + (size_t)d * NCOLS));
    }
}

extern "C" void kernel_launch(void* const* d_in, const int* in_sizes, int n_in,
                              void* d_out, int out_size, void* d_ws, size_t ws_size,
                              hipStream_t stream) {
    const float* ZPi   = (const float*)d_in[0];
    const float* U     = (const float*)d_in[1];
    const float* alpha = (const float*)d_in[2];
    float* out = (float*)d_out;

    dim3 grid(NCOLS / TILE);   // 2048 blocks
    dim3 block(256);           // 4 waves
    CCLayer_kernel<<<grid, block, 0, stream>>>(ZPi, U, alpha, out);
}